// Round 1
// baseline (334.993 us; speedup 1.0000x reference)
//
#include <hip/hip_runtime.h>

// ---------------------------------------------------------------------------
// unit_gcn: out[n,o,t,v] = BN(ReLU-after) of  sum_{s=0..24} Ws[s] @_c x[n,:,t,(v+s)%25]
//   Ws[0] = S0 = sum_i W[i,:,:,0];  Ws[s] = W[s-1,:,:,1]  (s>=1)
//   bias b cancels under training-mode BatchNorm (channel-constant shift).
// N=64, C=64, T=300, V=25, O=64.  x fp32 -> bf16 MFMA (16x16x32), fp32 accum.
// ---------------------------------------------------------------------------

typedef short  s16x8 __attribute__((ext_vector_type(8)));
typedef float  f32x4 __attribute__((ext_vector_type(4)));

#define T_      300
#define TB_     19          // ceil(300/16) t-blocks
#define NTHR_   320         // 5 waves per block

__device__ __forceinline__ unsigned short f2bf(float f) {
  unsigned u = __builtin_bit_cast(unsigned, f);
  return (unsigned short)((u + 0x7FFFu + ((u >> 16) & 1u)) >> 16);
}

// --- P0: pack Ws into MFMA B-fragment layout -------------------------------
// Wg entry idx = ((s*2+chunk)*4 + ni)*64 + lane ; 8 bf16 per entry:
//   elem j = Ws[s][ o = ni*16 + (lane&15) ][ c = chunk*32 + (lane>>4)*8 + j ]
__global__ void pack_w_kernel(const float* __restrict__ W, s16x8* __restrict__ Wg) {
  int idx = blockIdx.x * 256 + threadIdx.x;
  if (idx >= 12800) return;
  int lane  = idx & 63;
  int ni    = (idx >> 6) & 3;
  int chunk = (idx >> 8) & 1;
  int s     = idx >> 9;
  int o     = (ni << 4) + (lane & 15);
  int cbase = (chunk << 5) + ((lane >> 4) << 3);
  s16x8 h;
#pragma unroll
  for (int j = 0; j < 8; ++j) {
    int c = cbase + j;
    float val;
    if (s == 0) {
      val = 0.f;
      for (int i = 0; i < 24; ++i) val += W[((i * 64 + o) * 64 + c) * 2];
    } else {
      val = W[(((s - 1) * 64 + o) * 64 + c) * 2 + 1];
    }
    h[j] = (short)f2bf(val);
  }
  Wg[idx] = h;
}

// --- P1: main tap-GEMM -----------------------------------------------------
// grid (n=64, tb=19), 320 threads = 5 waves. Block owns rows (t_local,v)=400,
// cols o=64. A-slab [400][64c] bf16 in LDS, row stride 128B, byte^((row&7)<<4).
// Wave w: row-tiles rt = w*5..w*5+4 (each 16 rows) x 4 col-tiles. acc 5x4 f32x4.
__global__ __launch_bounds__(NTHR_) void tap_mm_kernel(
    const float* __restrict__ x, const s16x8* __restrict__ Wg,
    float* __restrict__ out, float* __restrict__ partials) {
  __shared__ __align__(16) char Ash[51200];
  int n  = blockIdx.x;
  int tb = blockIdx.y;
  int t0 = tb * 16;
  int validRows = min(16, T_ - t0) * 25;
  int tid = threadIdx.x;
  const float* xn = x + n * 480000 + t0 * 25;

  // ---- stage A: per task, 8 c-values (strided global) -> one 16B ds_write
  for (int it = 0; it < 10; ++it) {
    int id  = tid + it * NTHR_;        // 0..3199  = cgroup*400 + pos
    int pos = id % 400;                // t_local*25 + u  (contiguous in x!)
    int c0  = (id / 400) << 3;
    bool vld = pos < validRows;
    s16x8 h;
#pragma unroll
    for (int j = 0; j < 8; ++j) {
      float f = vld ? xn[(c0 + j) * 7500 + pos] : 0.f;
      h[j] = (short)f2bf(f);
    }
    int off = ((pos << 7) + (c0 << 1)) ^ ((pos & 7) << 4);
    *(s16x8*)(Ash + off) = h;
  }
  __syncthreads();

  int wid = tid >> 6, lane = tid & 63;
  int l15 = lane & 15, lk = lane >> 4;
  int tL[5], vv[5];
#pragma unroll
  for (int r = 0; r < 5; ++r) {
    int orow = ((wid * 5 + r) << 4) + l15;   // output row this lane owns (A-side)
    tL[r] = orow / 25;
    vv[r] = orow - tL[r] * 25;
  }
  f32x4 acc[5][4];
#pragma unroll
  for (int r = 0; r < 5; ++r)
#pragma unroll
    for (int ct = 0; ct < 4; ++ct) acc[r][ct] = (f32x4){0.f, 0.f, 0.f, 0.f};

  // B-fragments: global->reg, double-buffered (L2-resident 200KB, all waves share)
  s16x8 bf[2][4];
#pragma unroll
  for (int ni = 0; ni < 4; ++ni) bf[0][ni] = Wg[(ni << 6) + lane];

#pragma unroll 2
  for (int q = 0; q < 50; ++q) {       // q = s*2 + chunk
    int cur = q & 1;
    if (q < 49) {
#pragma unroll
      for (int ni = 0; ni < 4; ++ni)
        bf[cur ^ 1][ni] = Wg[((q + 1) << 8) + (ni << 6) + lane];
    }
    int s = q >> 1, chunk = q & 1;
    s16x8 af[5];
#pragma unroll
    for (int r = 0; r < 5; ++r) {
      int u = vv[r] + s;
      u -= (u >= 25) ? 25 : 0;
      int srow = tL[r] * 25 + u;       // shifted source row, same t, in-slab
      int off = ((srow << 7) + (chunk << 6) + (lk << 4)) ^ ((srow & 7) << 4);
      af[r] = *(const s16x8*)(Ash + off);
    }
#pragma unroll
    for (int r = 0; r < 5; ++r)
#pragma unroll
      for (int ct = 0; ct < 4; ++ct)
        acc[r][ct] = __builtin_amdgcn_mfma_f32_16x16x32_bf16(
            af[r], bf[cur][ct], acc[r][ct], 0, 0, 0);
  }
  __syncthreads();  // all waves done reading Ash; reuse it as reduction buffer

  // ---- epilogue: store raw GEMM + per-column (o) sum / sumsq
  float s1v[4] = {0.f, 0.f, 0.f, 0.f}, s2v[4] = {0.f, 0.f, 0.f, 0.f};
#pragma unroll
  for (int r = 0; r < 5; ++r) {
#pragma unroll
    for (int qq = 0; qq < 4; ++qq) {
      int orow = ((wid * 5 + r) << 4) + (lk << 2) + qq;  // C/D: row=(l>>4)*4+reg
      if (orow < validRows) {
        int tt  = orow / 25;
        int vv2 = orow - tt * 25;
        int rowaddr = n * 480000 + (t0 + tt) * 25 + vv2;
#pragma unroll
        for (int ct = 0; ct < 4; ++ct) {
          float val = acc[r][ct][qq];
          s1v[ct] += val;
          s2v[ct] += val * val;
          int o = (ct << 4) + l15;                        // C/D: col=lane&15
          out[rowaddr + o * 7500] = val;
        }
      }
    }
  }
  float* red = (float*)Ash;
#pragma unroll
  for (int ct = 0; ct < 4; ++ct) {
    float a = s1v[ct], b = s2v[ct];
    a += __shfl_xor(a, 16); a += __shfl_xor(a, 32);
    b += __shfl_xor(b, 16); b += __shfl_xor(b, 32);
    if (lane < 16) {
      int base = ((((wid << 2) + ct) << 4) + l15) * 2;
      red[base]     = a;
      red[base + 1] = b;
    }
  }
  __syncthreads();
  if (tid < 128) {  // deterministic fixed-order block reduction, no atomics
    int o = tid >> 1, m = tid & 1;
    int ct = o >> 4, ol = o & 15;
    float sres = 0.f;
#pragma unroll
    for (int w = 0; w < 5; ++w) sres += red[((((w << 2) + ct) << 4) + ol) * 2 + m];
    int bl = blockIdx.y * 64 + blockIdx.x;
    partials[bl * 128 + m * 64 + o] = sres;
  }
}

// --- P2: reduce per-block partials -> per-channel scale/shift --------------
__global__ void finalize_kernel(const float* __restrict__ part,
                                const float* __restrict__ gamma,
                                const float* __restrict__ beta,
                                float* __restrict__ scsh) {
  __shared__ float accs[512];
  int tid = threadIdx.x;           // 512 threads
  int om = tid & 127, p = tid >> 7;
  float s = 0.f;
  for (int b = p; b < 1216; b += 4) s += part[b * 128 + om];
  accs[tid] = s;
  __syncthreads();
  if (tid < 128) accs[tid] = accs[tid] + accs[tid + 128] + accs[tid + 256] + accs[tid + 384];
  __syncthreads();
  if (tid < 64) {
    float s1 = accs[tid], s2 = accs[tid + 64];
    const float inv = 1.0f / 480000.0f;
    float mean = s1 * inv;
    float var  = s2 * inv - mean * mean;
    float sc = gamma[tid] * rsqrtf(var + 1e-5f);
    float sh = beta[tid] - mean * sc;
    scsh[tid]      = sc;
    scsh[64 + tid] = sh;
  }
}

// --- P3: in-place BN-apply + ReLU, float4 ----------------------------------
__global__ void bn_relu_kernel(float4* __restrict__ out, const float* __restrict__ scsh) {
  int i = blockIdx.x * blockDim.x + threadIdx.x;
  const int total = 7680000;        // 30.72M / 4 ; 7500%4==0 so o uniform per f4
  int stride = gridDim.x * blockDim.x;
  for (; i < total; i += stride) {
    int o = (i / 1875) & 63;
    float sc = scsh[o], sh = scsh[64 + o];
    float4 v = out[i];
    v.x = fmaxf(fmaf(v.x, sc, sh), 0.f);
    v.y = fmaxf(fmaf(v.y, sc, sh), 0.f);
    v.z = fmaxf(fmaf(v.z, sc, sh), 0.f);
    v.w = fmaxf(fmaf(v.w, sc, sh), 0.f);
    out[i] = v;
  }
}

// ---------------------------------------------------------------------------
extern "C" void kernel_launch(void* const* d_in, const int* in_sizes, int n_in,
                              void* d_out, int out_size, void* d_ws, size_t ws_size,
                              hipStream_t stream) {
  const float* x     = (const float*)d_in[0];
  const float* W     = (const float*)d_in[1];
  // d_in[2] = b : cancels under batch-norm, unused.
  const float* gamma = (const float*)d_in[3];
  const float* beta  = (const float*)d_in[4];
  float* out = (float*)d_out;

  char* ws = (char*)d_ws;
  s16x8* Wg       = (s16x8*)ws;                       // 204,800 B
  float* partials = (float*)(ws + 204800);            // 1216*128*4 = 622,592 B
  float* scsh     = (float*)(ws + 204800 + 622592);   // 512 B

  pack_w_kernel<<<dim3(50), dim3(256), 0, stream>>>(W, Wg);
  tap_mm_kernel<<<dim3(64, TB_), dim3(NTHR_), 0, stream>>>(x, Wg, out, partials);
  finalize_kernel<<<dim3(1), dim3(512), 0, stream>>>(partials, gamma, beta, scsh);
  bn_relu_kernel<<<dim3(2048), dim3(256), 0, stream>>>((float4*)out, scsh);
}

// Round 2
// 216.932 us; speedup vs baseline: 1.5442x; 1.5442x over previous
//
#include <hip/hip_runtime.h>

// ---------------------------------------------------------------------------
// unit_gcn: out[n,o,t,v] = BN+ReLU of  sum_{s=0..24} Ws[s] @_c x[n,:,t,(v+s)%25]
//   Ws[0] = sum_i W[i,:,:,0];  Ws[s] = W[s-1,:,:,1]  (s>=1); bias cancels in BN.
// N=64, C=64, T=300, V=25, O=64.  x fp32 -> bf16 MFMA (16x16x32), fp32 accum.
// ---------------------------------------------------------------------------

typedef short  s16x8 __attribute__((ext_vector_type(8)));
typedef float  f32x4 __attribute__((ext_vector_type(4)));

#define T_      300
#define TB_     19          // ceil(300/16) t-blocks
#define NTHR_   320         // 5 waves per block

__device__ __forceinline__ unsigned short f2bf(float f) {
  unsigned u = __builtin_bit_cast(unsigned, f);
  return (unsigned short)((u + 0x7FFFu + ((u >> 16) & 1u)) >> 16);
}

// --- P0: pack Ws into MFMA B-fragment layout -------------------------------
// Wg entry idx = ((s*2+chunk)*4 + ni)*64 + lane ; 8 bf16 per entry:
//   elem j = Ws[s][ o = ni*16 + (lane&15) ][ c = chunk*32 + (lane>>4)*8 + j ]
__global__ void pack_w_kernel(const float* __restrict__ W, s16x8* __restrict__ Wg) {
  int idx = blockIdx.x * 256 + threadIdx.x;
  if (idx >= 12800) return;
  int lane  = idx & 63;
  int ni    = (idx >> 6) & 3;
  int chunk = (idx >> 8) & 1;
  int s     = idx >> 9;
  int o     = (ni << 4) + (lane & 15);
  int cbase = (chunk << 5) + ((lane >> 4) << 3);
  s16x8 h;
#pragma unroll
  for (int j = 0; j < 8; ++j) {
    int c = cbase + j;
    float val;
    if (s == 0) {
      val = 0.f;
      for (int i = 0; i < 24; ++i) val += W[((i * 64 + o) * 64 + c) * 2];
    } else {
      val = W[(((s - 1) * 64 + o) * 64 + c) * 2 + 1];
    }
    h[j] = (short)f2bf(val);
  }
  Wg[idx] = h;
}

// --- P1: main tap-GEMM -----------------------------------------------------
// grid (n=64, tb=19), 320 threads = 5 waves. Block owns rows (t_local,v)=400,
// cols o=64. A-slab [400 rows][64 c] bf16 in LDS, stride 128B, ^((row&7)<<4).
// Wave w: 5 row-tiles x 4 col-tiles, acc 5x4 f32x4. Software-pipelined.
__global__ __launch_bounds__(NTHR_) void tap_mm_kernel(
    const float* __restrict__ x, const s16x8* __restrict__ Wg,
    float* __restrict__ out, float* __restrict__ partials) {
  __shared__ __align__(16) char Ash[51200];   // A-slab; later T[32 o][400 rows] f32
  __shared__ float red2[640];
  int n  = blockIdx.x;
  int tb = blockIdx.y;
  int t0 = tb * 16;
  int validRows = min(16, T_ - t0) * 25;
  int tid = threadIdx.x;
  const float* xn = x + n * 480000 + t0 * 25;

  // ---- stage A: 8 strided c-values -> one 16B ds_write (conflict-free)
#pragma unroll 5
  for (int it = 0; it < 10; ++it) {
    int id  = tid + it * NTHR_;        // cgroup*400 + pos
    int pos = id % 400;                // t_local*25 + u (contiguous in x)
    int c0  = (id / 400) << 3;
    bool vld = pos < validRows;
    s16x8 h;
#pragma unroll
    for (int j = 0; j < 8; ++j) {
      float f = vld ? xn[(c0 + j) * 7500 + pos] : 0.f;
      h[j] = (short)f2bf(f);
    }
    int off = ((pos << 7) + (c0 << 1)) ^ ((pos & 7) << 4);
    *(s16x8*)(Ash + off) = h;
  }
  __syncthreads();

  int wid = tid >> 6, lane = tid & 63;
  int l15 = lane & 15, lk = lane >> 4;
  int tL[5], u[5];
#pragma unroll
  for (int r = 0; r < 5; ++r) {
    int orow = ((wid * 5 + r) << 4) + l15;   // output row this lane feeds (A-side)
    tL[r] = orow / 25;
    u[r]  = orow - tL[r] * 25;               // starts at v; advances with s
  }
  f32x4 acc[5][4];
#pragma unroll
  for (int r = 0; r < 5; ++r)
#pragma unroll
    for (int ct = 0; ct < 4; ++ct) acc[r][ct] = (f32x4){0.f, 0.f, 0.f, 0.f};

  // B-frags: chunk0 (bfA) + chunk1 (bfB) of current s, global->reg (L2-hot)
  s16x8 bfA[4], bfB[4];
#pragma unroll
  for (int ni = 0; ni < 4; ++ni) bfA[ni] = Wg[(ni << 6) + lane];         // q=0
#pragma unroll
  for (int ni = 0; ni < 4; ++ni) bfB[ni] = Wg[256 + (ni << 6) + lane];   // q=1

  // A-frags: afA = frag(s=0, chunk0); rotate-register pipeline (6 frags live)
  s16x8 afA[5];
#pragma unroll
  for (int r = 0; r < 5; ++r) {
    int srow = tL[r] * 25 + u[r];
    int off  = (srow << 7) + ((lk << 4) ^ ((srow & 7) << 4));
    afA[r] = *(const s16x8*)(Ash + off);
  }

  for (int s = 0; s < 25; ++s) {
    // --- phase A: consume chunk0 frags; load chunk1 frags into their place
    __builtin_amdgcn_s_setprio(1);
#pragma unroll
    for (int r = 0; r < 5; ++r) {
      int srow = tL[r] * 25 + u[r];
      int off  = (srow << 7) + ((64 | (lk << 4)) ^ ((srow & 7) << 4));
      s16x8 t = *(const s16x8*)(Ash + off);
#pragma unroll
      for (int ct = 0; ct < 4; ++ct)
        acc[r][ct] = __builtin_amdgcn_mfma_f32_16x16x32_bf16(
            afA[r], bfA[ct], acc[r][ct], 0, 0, 0);
      afA[r] = t;
    }
    __builtin_amdgcn_s_setprio(0);
    // reload bfA for s+1 (bfA dead now); clamp index on last iter (dummy)
    int qA = (s < 24) ? (2 * s + 2) : 0;
#pragma unroll
    for (int ni = 0; ni < 4; ++ni) bfA[ni] = Wg[(qA << 8) + (ni << 6) + lane];
    // advance shift
#pragma unroll
    for (int r = 0; r < 5; ++r) u[r] = (u[r] == 24) ? 0 : u[r] + 1;
    // --- phase B: consume chunk1 frags; load next-s chunk0 frags
    __builtin_amdgcn_s_setprio(1);
#pragma unroll
    for (int r = 0; r < 5; ++r) {
      int srow = tL[r] * 25 + u[r];
      int off  = (srow << 7) + ((lk << 4) ^ ((srow & 7) << 4));
      s16x8 t = *(const s16x8*)(Ash + off);   // harmless dummy on s==24
#pragma unroll
      for (int ct = 0; ct < 4; ++ct)
        acc[r][ct] = __builtin_amdgcn_mfma_f32_16x16x32_bf16(
            afA[r], bfB[ct], acc[r][ct], 0, 0, 0);
      afA[r] = t;
    }
    __builtin_amdgcn_s_setprio(0);
    int qB = (s < 24) ? (2 * s + 3) : 1;
#pragma unroll
    for (int ni = 0; ni < 4; ++ni) bfB[ni] = Wg[(qB << 8) + (ni << 6) + lane];
  }

  // ---- per-channel sum/sumsq from registers (valid rows only)
  float s1v[4] = {0.f, 0.f, 0.f, 0.f}, s2v[4] = {0.f, 0.f, 0.f, 0.f};
#pragma unroll
  for (int r = 0; r < 5; ++r) {
#pragma unroll
    for (int qq = 0; qq < 4; ++qq) {
      int orow = ((wid * 5 + r) << 4) + (lk << 2) + qq;  // C/D: row=(l>>4)*4+reg
      if (orow < validRows) {
#pragma unroll
        for (int ct = 0; ct < 4; ++ct) {
          float val = acc[r][ct][qq];
          s1v[ct] += val;
          s2v[ct] += val * val;
        }
      }
    }
  }
#pragma unroll
  for (int ct = 0; ct < 4; ++ct) {
    float a = s1v[ct], b = s2v[ct];
    a += __shfl_xor(a, 16); a += __shfl_xor(a, 32);
    b += __shfl_xor(b, 16); b += __shfl_xor(b, 32);
    if (lane < 16) {
      int base = ((((wid << 2) + ct) << 4) + l15) * 2;
      red2[base]     = a;
      red2[base + 1] = b;
    }
  }

  // ---- epilogue: two o-halves through LDS transpose, coalesced f4 stores
  float* T = (float*)Ash;
  float* outb = out + n * 480000 + tb * 400;   // + o*7500 + row
#pragma unroll
  for (int h = 0; h < 2; ++h) {
    __syncthreads();   // h=0: all af reads + red2 writes done; h=1: reads of T done
    // write acc -> T[o_local][row]  (f4, conflict-free: group = 4*(l15&1)+lk)
#pragma unroll
    for (int r = 0; r < 5; ++r)
#pragma unroll
      for (int ctl = 0; ctl < 2; ++ctl) {
        int o_local = (ctl << 4) + l15;
        int row0    = wid * 80 + r * 16 + (lk << 2);
        *(f32x4*)&T[o_local * 400 + row0] = acc[r][(h << 1) + ctl];
      }
    __syncthreads();
    if (h == 0 && tid < 128) {   // deterministic partial reduction (reads red2)
      int o = tid >> 1, m = tid & 1;
      int ct = o >> 4, ol = o & 15;
      float sres = 0.f;
#pragma unroll
      for (int w = 0; w < 5; ++w) sres += red2[((((w << 2) + ct) << 4) + ol) * 2 + m];
      int bl = blockIdx.y * 64 + blockIdx.x;
      partials[bl * 128 + m * 64 + o] = sres;
    }
    // read T + coalesced global f4 stores: 32 o x 100 f4-rows
#pragma unroll
    for (int i = 0; i < 10; ++i) {
      int idx = tid + i * 320;
      int ol  = idx / 100;
      int r4  = idx - ol * 100;
      if ((r4 << 2) < validRows) {
        float4 v = *(float4*)&T[ol * 400 + (r4 << 2)];
        *(float4*)&outb[((h << 5) + ol) * 7500 + (r4 << 2)] = v;
      }
    }
  }
}

// --- P2: reduce per-block partials -> per-channel scale/shift --------------
__global__ void finalize_kernel(const float* __restrict__ part,
                                const float* __restrict__ gamma,
                                const float* __restrict__ beta,
                                float* __restrict__ scsh) {
  __shared__ float sm[512];
  int o = blockIdx.x;            // 64 blocks, one channel each
  int tid = threadIdx.x;         // 256 threads
  float s1 = 0.f, s2 = 0.f;
  for (int b = tid; b < 1216; b += 256) {
    s1 += part[b * 128 + o];
    s2 += part[b * 128 + 64 + o];
  }
  sm[tid] = s1; sm[256 + tid] = s2;
  __syncthreads();
  for (int st = 128; st >= 1; st >>= 1) {
    if (tid < st) { sm[tid] += sm[tid + st]; sm[256 + tid] += sm[256 + tid + st]; }
    __syncthreads();
  }
  if (tid == 0) {
    const float inv = 1.0f / 480000.0f;
    float mean = sm[0] * inv;
    float var  = sm[256] * inv - mean * mean;
    float sc = gamma[o] * rsqrtf(var + 1e-5f);
    float sh = beta[o] - mean * sc;
    scsh[o]      = sc;
    scsh[64 + o] = sh;
  }
}

// --- P3: in-place BN-apply + ReLU, float4 ----------------------------------
__global__ void bn_relu_kernel(float4* __restrict__ out, const float* __restrict__ scsh) {
  int i = blockIdx.x * blockDim.x + threadIdx.x;
  const int total = 7680000;        // 30.72M / 4 ; 7500%4==0 so o uniform per f4
  int stride = gridDim.x * blockDim.x;
  for (; i < total; i += stride) {
    int o = (i / 1875) & 63;
    float sc = scsh[o], sh = scsh[64 + o];
    float4 v = out[i];
    v.x = fmaxf(fmaf(v.x, sc, sh), 0.f);
    v.y = fmaxf(fmaf(v.y, sc, sh), 0.f);
    v.z = fmaxf(fmaf(v.z, sc, sh), 0.f);
    v.w = fmaxf(fmaf(v.w, sc, sh), 0.f);
    out[i] = v;
  }
}

// ---------------------------------------------------------------------------
extern "C" void kernel_launch(void* const* d_in, const int* in_sizes, int n_in,
                              void* d_out, int out_size, void* d_ws, size_t ws_size,
                              hipStream_t stream) {
  const float* x     = (const float*)d_in[0];
  const float* W     = (const float*)d_in[1];
  // d_in[2] = b : cancels under batch-norm, unused.
  const float* gamma = (const float*)d_in[3];
  const float* beta  = (const float*)d_in[4];
  float* out = (float*)d_out;

  char* ws = (char*)d_ws;
  s16x8* Wg       = (s16x8*)ws;                       // 204,800 B
  float* partials = (float*)(ws + 204800);            // 1216*128*4 = 622,592 B
  float* scsh     = (float*)(ws + 204800 + 622592);   // 512 B

  pack_w_kernel<<<dim3(50), dim3(256), 0, stream>>>(W, Wg);
  tap_mm_kernel<<<dim3(64, TB_), dim3(NTHR_), 0, stream>>>(x, Wg, out, partials);
  finalize_kernel<<<dim3(64), dim3(256), 0, stream>>>(partials, gamma, beta, scsh);
  bn_relu_kernel<<<dim3(2048), dim3(256), 0, stream>>>((float4*)out, scsh);
}